// Round 8
// baseline (355.930 us; speedup 1.0000x reference)
//
#include <hip/hip_runtime.h>
#include <math.h>

#define DD 4096
#define EE 64
#define NTOK 8192
#define BM 512           // tokens per block (lane owns 8: mm*64+lane)
#define KC 16            // K-chunk staged in LDS
#define KCP 20           // row stride (words): 80 B = 16B-aligned, conflict-free
#define NMB (NTOK / BM)  // 16 m-blocks
#define TAU 1e-3f        // near-tie flag threshold (f32 err worst-case ~1e-5)

// ---------------------------------------------------------------------------
// gemm (f32): block = 512 thr (8 waves) = 512 tok x 64 exp. Wave w owns
// experts 8w..8w+7; lane owns tokens mm*64+lane. Per lane per k: 32 B x +
// 32 B w from LDS for 64 FMAs (1.0 B/FMA). x rows stride-20 words ->
// conflict-free b128; w reads wave-uniform broadcast. Reg-prefetch, single
// LDS buffer, 2 barriers/chunk. Partials -> part[ks][token][e].
// ---------------------------------------------------------------------------
__global__ __launch_bounds__(512, 2) void moirai_gemm(
        const float* __restrict__ x, const float* __restrict__ W,
        float* __restrict__ part, int* __restrict__ count, int kslen) {
    __shared__ float xs[BM][KCP];    // 40 KB
    __shared__ float wsh[EE][KCP];   //  5 KB

    const int t    = threadIdx.x;
    const int lane = t & 63;
    const int e0   = (t >> 6) * 8;        // wave's expert base
    const int mblk = blockIdx.x & (NMB - 1);
    const int ks   = blockIdx.x >> 4;     // grid = NMB * KS, NMB = 16
    const int m0   = mblk * BM;
    const int k0   = ks * kslen;

    if (blockIdx.x == 0 && t == 0) *count = 0;

    // staging indices: x = 2048 float4 (4/thr), w = 256 float4 (t<256)
    const int xrow = t >> 2;              // 0..127 (+ i*128)
    const int xseg = t & 3;               // 16B segment in 16-f32 row-chunk
    const int wrow = t >> 2;              // 0..63 for t<256
    const int wseg = t & 3;

    float acc[8][8];
#pragma unroll
    for (int mm = 0; mm < 8; mm++)
#pragma unroll
        for (int ee = 0; ee < 8; ee++) acc[mm][ee] = 0.0f;

    const int nch = kslen / KC;
    float4 xr[4], wr;

    auto load_regs = [&](int c) {
        const int kb = k0 + c * KC;
#pragma unroll
        for (int i = 0; i < 4; i++)
            xr[i] = *(const float4*)(x + (size_t)(m0 + xrow + i * 128) * DD
                                       + kb + xseg * 4);
        if (t < 256)
            wr = *(const float4*)(W + (size_t)wrow * DD + kb + wseg * 4);
    };
    auto store_lds = [&]() {
#pragma unroll
        for (int i = 0; i < 4; i++)
            *(float4*)&xs[xrow + i * 128][xseg * 4] = xr[i];
        if (t < 256)
            *(float4*)&wsh[wrow][wseg * 4] = wr;
    };

    load_regs(0);
    store_lds();
    __syncthreads();

    for (int c = 0; c < nch; c++) {
        if (c + 1 < nch) load_regs(c + 1);   // global prefetch under compute

#pragma unroll
        for (int kk = 0; kk < KC; kk += 4) {
            float4 wq[8];
#pragma unroll
            for (int ee = 0; ee < 8; ee++)
                wq[ee] = *(const float4*)&wsh[e0 + ee][kk];   // broadcast
#pragma unroll
            for (int mm = 0; mm < 8; mm++) {
                const float4 xq = *(const float4*)&xs[mm * 64 + lane][kk];
#pragma unroll
                for (int ee = 0; ee < 8; ee++) {
                    acc[mm][ee] = fmaf(xq.x, wq[ee].x, acc[mm][ee]);
                    acc[mm][ee] = fmaf(xq.y, wq[ee].y, acc[mm][ee]);
                    acc[mm][ee] = fmaf(xq.z, wq[ee].z, acc[mm][ee]);
                    acc[mm][ee] = fmaf(xq.w, wq[ee].w, acc[mm][ee]);
                }
            }
        }

        if (c + 1 < nch) {
            __syncthreads();     // all reads of current chunk done
            store_lds();
            __syncthreads();     // staging visible
        }
    }

    // epilogue: lane writes 8 token-rows x 8 experts (2x b128 per row)
#pragma unroll
    for (int mm = 0; mm < 8; mm++) {
        float* po = part + ((size_t)ks * NTOK + (m0 + mm * 64 + lane)) * EE + e0;
        float4 o1 = {acc[mm][0], acc[mm][1], acc[mm][2], acc[mm][3]};
        float4 o2 = {acc[mm][4], acc[mm][5], acc[mm][6], acc[mm][7]};
        *(float4*)(po)     = o1;
        *(float4*)(po + 4) = o2;
    }
}

// ---------------------------------------------------------------------------
// topk pass 1: wave per token, lane = expert. f32 sum of KS partials + bias
// -> top-2 + third-max. Near-tie rows appended to flagged list (fix kernel
// overwrites them). Output: [gate_probs 16384 f32][indices-as-f32 16384].
// ---------------------------------------------------------------------------
__global__ void moirai_topk(const float* __restrict__ part,
                            const float* __restrict__ bias,
                            float* __restrict__ out,
                            int* __restrict__ count, int* __restrict__ list,
                            int KS) {
    const int lane  = threadIdx.x & 63;
    const int token = blockIdx.x * 4 + (threadIdx.x >> 6);

    float v = bias[lane];
    for (int ks = 0; ks < KS; ks++)
        v += part[((size_t)ks * NTOK + token) * EE + lane];

    // f32 top-2 butterfly with jax tie-break (lower index wins ties)
    float v1 = v, v2 = -3.4e38f;
    int   i1 = lane, i2 = 127;
#pragma unroll
    for (int off = 1; off < 64; off <<= 1) {
        float u1 = __shfl_xor(v1, off);
        float u2 = __shfl_xor(v2, off);
        int   j1 = __shfl_xor(i1, off);
        int   j2 = __shfl_xor(i2, off);
        bool u1_beats_v1 = (u1 > v1) || (u1 == v1 && j1 < i1);
        if (u1_beats_v1) {
            bool v1_beats_u2 = (v1 > u2) || (v1 == u2 && i1 < j2);
            if (v1_beats_u2) { v2 = v1; i2 = i1; }
            else             { v2 = u2; i2 = j2; }
            v1 = u1; i1 = j1;
        } else {
            bool u1_beats_v2 = (u1 > v2) || (u1 == v2 && j1 < i2);
            if (u1_beats_v2) { v2 = u1; i2 = j1; }
        }
    }

    // third-largest value (exclude top-2 by index)
    float ve = (lane == i1 || lane == i2) ? -3.4e38f : v;
#pragma unroll
    for (int off = 1; off < 64; off <<= 1)
        ve = fmaxf(ve, __shfl_xor(ve, off));

    if (lane == 0) {
        if ((v1 - v2 < TAU) || (v2 - ve < TAU)) {
            int pos = atomicAdd(count, 1);
            list[pos] = token;
        }
        double ex = exp((double)v2 - (double)v1);   // v1 >= v2 -> stable
        double s  = 1.0 + ex;
        out[token * 2 + 0] = (float)(1.0 / s);
        out[token * 2 + 1] = (float)(ex / s);
        out[NTOK * 2 + token * 2 + 0] = (float)i1;
        out[NTOK * 2 + token * 2 + 1] = (float)i2;
    }
}

// ---------------------------------------------------------------------------
// fix: exact f64 recompute of flagged rows, one block (1024 thr) per row.
// thread t: expert t&63, k-slice t>>6 (16 x 256). LDS reduce -> wave 0 does
// f64 top-2 (validated tie-break) and overwrites the row's outputs.
// ---------------------------------------------------------------------------
__global__ __launch_bounds__(1024) void moirai_fix(
        const float* __restrict__ x, const float* __restrict__ W,
        const float* __restrict__ bias,
        const int* __restrict__ count, const int* __restrict__ list,
        float* __restrict__ out) {
    __shared__ double red[16][EE];

    const int t = threadIdx.x;
    const int e = t & 63;
    const int q = t >> 6;           // 16 k-slices of 256
    const int n = *count;

    for (int idx = blockIdx.x; idx < n; idx += gridDim.x) {
        const int token = list[idx];
        const float* xr = x + (size_t)token * DD + q * (DD / 16);
        const float* wr = W + (size_t)e * DD + q * (DD / 16);

        double a0 = 0.0, a1 = 0.0, a2 = 0.0, a3 = 0.0;
#pragma unroll 4
        for (int k = 0; k < DD / 16; k += 4) {
            const float4 xv = *(const float4*)(xr + k);
            const float4 wv = *(const float4*)(wr + k);
            a0 += (double)xv.x * (double)wv.x;
            a1 += (double)xv.y * (double)wv.y;
            a2 += (double)xv.z * (double)wv.z;
            a3 += (double)xv.w * (double)wv.w;
        }
        red[q][e] = (a0 + a1) + (a2 + a3);
        __syncthreads();

        if (q == 0) {
            double vd = 0.0;
#pragma unroll
            for (int qq = 0; qq < 16; qq++) vd += red[qq][e];   // fixed order
            vd += (double)bias[e];

            double e1 = vd, e2 = -1.0e300;
            int    f1 = e,  f2 = 127;
#pragma unroll
            for (int off = 1; off < 64; off <<= 1) {
                double u1 = __shfl_xor(e1, off);
                double u2 = __shfl_xor(e2, off);
                int    j1 = __shfl_xor(f1, off);
                int    j2 = __shfl_xor(f2, off);
                bool u1_beats_e1 = (u1 > e1) || (u1 == e1 && j1 < f1);
                if (u1_beats_e1) {
                    bool e1_beats_u2 = (e1 > u2) || (e1 == u2 && f1 < j2);
                    if (e1_beats_u2) { e2 = e1; f2 = f1; }
                    else             { e2 = u2; f2 = j2; }
                    e1 = u1; f1 = j1;
                } else {
                    bool u1_beats_e2 = (u1 > e2) || (u1 == e2 && j1 < f2);
                    if (u1_beats_e2) { e2 = u1; f2 = j1; }
                }
            }

            if (e == 0) {
                double ex = exp(e2 - e1);
                double s  = 1.0 + ex;
                out[token * 2 + 0] = (float)(1.0 / s);
                out[token * 2 + 1] = (float)(ex / s);
                out[NTOK * 2 + token * 2 + 0] = (float)f1;
                out[NTOK * 2 + token * 2 + 1] = (float)f2;
            }
        }
        __syncthreads();   // LDS reuse guard for next grid-stride iteration
    }
}

// ---------------------------------------------------------------------------
extern "C" void kernel_launch(void* const* d_in, const int* in_sizes, int n_in,
                              void* d_out, int out_size, void* d_ws, size_t ws_size,
                              hipStream_t stream) {
    const float* x = (const float*)d_in[0];
    const float* W = (const float*)d_in[1];
    const float* b = (const float*)d_in[2];
    float* out = (float*)d_out;

    // ws layout: [count 4B | list NTOK*4B] padded to 64 KB, then partials
    const size_t HDR = 65536;
    int*   count = (int*)d_ws;
    int*   list  = (int*)d_ws + 1;
    float* part  = (float*)((char*)d_ws + HDR);

    int KS = 16;  // K-split; kslen stays a multiple of KC
    while (KS > 1 && HDR + (size_t)KS * NTOK * EE * 4 > ws_size) KS >>= 1;
    const int kslen = DD / KS;

    moirai_gemm<<<NMB * KS, 512, 0, stream>>>(x, W, part, count, kslen);
    moirai_topk<<<NTOK / 4, 256, 0, stream>>>(part, b, out, count, list, KS);
    moirai_fix<<<256, 1024, 0, stream>>>(x, W, b, count, list, out);
}

// Round 9
// 87.917 us; speedup vs baseline: 4.0485x; 4.0485x over previous
//
#include <hip/hip_runtime.h>
#include <math.h>

#define DD 4096
#define EE 64
#define NTOK 8192
#define BM 128           // tokens per block
#define KC 32            // K-chunk staged in LDS
#define XSTR 40          // LDS row stride in bf16 elems (80 B: aligned, ≤2-way)
#define NMB (NTOK / BM)  // 64 m-blocks
#define TAU 4e-3f        // flag threshold; split-bf16 worst-case err ~5e-4

typedef __attribute__((ext_vector_type(8))) short short8;
typedef __attribute__((ext_vector_type(4))) float f32x4;

__device__ __forceinline__ unsigned short f2bf(float f) {   // RNE bf16
    unsigned int u = __float_as_uint(f);
    return (unsigned short)((u + 0x7FFFu + ((u >> 16) & 1u)) >> 16);
}
__device__ __forceinline__ float bf2f(unsigned short h) {
    return __uint_as_float((unsigned int)h << 16);
}

// ---------------------------------------------------------------------------
// prep: W -> bf16 hi/lo split (Wh, Wl); also zero the flag counter.
// ---------------------------------------------------------------------------
__global__ void moirai_prep(const float* __restrict__ W,
                            unsigned short* __restrict__ Wh,
                            unsigned short* __restrict__ Wl,
                            int* __restrict__ count) {
    int i = blockIdx.x * 256 + threadIdx.x;
    if (i == 0) *count = 0;
    if (i < EE * DD) {
        float w = W[i];
        unsigned short h = f2bf(w);
        Wh[i] = h;
        Wl[i] = f2bf(w - bf2f(h));
    }
}

// ---------------------------------------------------------------------------
// gemm via 3-term split-bf16 MFMA (xh*wh + xh*wl + xl*wh), f32 accum.
// Block = 256 thr (2x2 waves) = 128 tok x 64 exp. Wave (wr,wc): m-tiles
// wr*4..+3, n-tiles wc*2..+1. x converted f32->bf16 hi/lo during staging.
// A/B fragments packed with IDENTICAL [row=lane&15][k=(lane>>4)*8+j] maps ->
// any k-permutation in HW cancels. C/D map is the m89/m91-verified one.
// Partials (f32) -> part[ks][token][e].
// ---------------------------------------------------------------------------
__global__ __launch_bounds__(256, 2) void moirai_gemm(
        const float* __restrict__ x,
        const unsigned short* __restrict__ Wh,
        const unsigned short* __restrict__ Wl,
        float* __restrict__ part, int kslen) {
    __shared__ __align__(16) unsigned short xs_h[BM * XSTR];  // 10 KB
    __shared__ __align__(16) unsigned short xs_l[BM * XSTR];  // 10 KB
    __shared__ __align__(16) unsigned short ws_h[EE * XSTR];  //  5 KB
    __shared__ __align__(16) unsigned short ws_l[EE * XSTR];  //  5 KB

    const int t    = threadIdx.x;
    const int lane = t & 63;
    const int wv   = t >> 6;
    const int wr   = wv >> 1;            // m half (0..1)
    const int wc   = wv & 1;             // n half (0..1)
    const int mblk = blockIdx.x & (NMB - 1);
    const int ks   = blockIdx.x >> 6;    // grid = NMB * KS, NMB = 64
    const int m0   = mblk * BM;
    const int k0   = ks * kslen;

    const int fr = lane & 15;            // row/col within 16x16 tile
    const int fg = lane >> 4;            // k-group

    float4 xr[4];
    uint4  whr, wlr;
    const int wrow = t >> 2;             // 0..63
    const int wseg = t & 3;              // 8-bf16 segment

    auto load_regs = [&](int c) {
        const int kb = k0 + c * KC;
#pragma unroll
        for (int i = 0; i < 4; i++) {
            const int idx = t + i * 256;
            const int row = idx >> 3, seg = idx & 7;
            xr[i] = *(const float4*)(x + (size_t)(m0 + row) * DD + kb + seg * 4);
        }
        whr = *(const uint4*)(Wh + (size_t)wrow * DD + kb + wseg * 8);
        wlr = *(const uint4*)(Wl + (size_t)wrow * DD + kb + wseg * 8);
    };
    auto store_lds = [&]() {
#pragma unroll
        for (int i = 0; i < 4; i++) {
            const int idx = t + i * 256;
            const int row = idx >> 3, seg = idx & 7;
            const float v[4] = {xr[i].x, xr[i].y, xr[i].z, xr[i].w};
            unsigned int h0, h1, l0, l1;
            {
                unsigned short a = f2bf(v[0]), b = f2bf(v[1]);
                unsigned short c2 = f2bf(v[2]), d = f2bf(v[3]);
                h0 = (unsigned int)a | ((unsigned int)b << 16);
                h1 = (unsigned int)c2 | ((unsigned int)d << 16);
                l0 = (unsigned int)f2bf(v[0] - bf2f(a))
                   | ((unsigned int)f2bf(v[1] - bf2f(b)) << 16);
                l1 = (unsigned int)f2bf(v[2] - bf2f(c2))
                   | ((unsigned int)f2bf(v[3] - bf2f(d)) << 16);
            }
            *(uint2*)&xs_h[row * XSTR + seg * 4] = uint2{h0, h1};
            *(uint2*)&xs_l[row * XSTR + seg * 4] = uint2{l0, l1};
        }
        *(uint4*)&ws_h[wrow * XSTR + wseg * 8] = whr;
        *(uint4*)&ws_l[wrow * XSTR + wseg * 8] = wlr;
    };

    f32x4 acc[4][2];
#pragma unroll
    for (int mt = 0; mt < 4; mt++)
#pragma unroll
        for (int nt = 0; nt < 2; nt++) acc[mt][nt] = f32x4{0.f, 0.f, 0.f, 0.f};

    const int nch = kslen / KC;
    load_regs(0);
    store_lds();
    __syncthreads();

    for (int c = 0; c < nch; c++) {
        if (c + 1 < nch) load_regs(c + 1);   // HBM prefetch under MFMA

        short8 ah[4], al[4], bh[2], bl[2];
#pragma unroll
        for (int mt = 0; mt < 4; mt++) {
            const int row = (wr * 4 + mt) * 16 + fr;
            ah[mt] = *(const short8*)&xs_h[row * XSTR + fg * 8];
            al[mt] = *(const short8*)&xs_l[row * XSTR + fg * 8];
        }
#pragma unroll
        for (int nt = 0; nt < 2; nt++) {
            const int row = (wc * 2 + nt) * 16 + fr;
            bh[nt] = *(const short8*)&ws_h[row * XSTR + fg * 8];
            bl[nt] = *(const short8*)&ws_l[row * XSTR + fg * 8];
        }
#pragma unroll
        for (int mt = 0; mt < 4; mt++)
#pragma unroll
            for (int nt = 0; nt < 2; nt++) {
                acc[mt][nt] = __builtin_amdgcn_mfma_f32_16x16x32_bf16(
                    ah[mt], bh[nt], acc[mt][nt], 0, 0, 0);
                acc[mt][nt] = __builtin_amdgcn_mfma_f32_16x16x32_bf16(
                    ah[mt], bl[nt], acc[mt][nt], 0, 0, 0);
                acc[mt][nt] = __builtin_amdgcn_mfma_f32_16x16x32_bf16(
                    al[mt], bh[nt], acc[mt][nt], 0, 0, 0);
            }

        if (c + 1 < nch) {
            __syncthreads();     // reads of current chunk done
            store_lds();
            __syncthreads();     // staging visible
        }
    }

    // C/D layout (verified m89/m91): col = lane&15, row = (lane>>4)*4 + j
#pragma unroll
    for (int mt = 0; mt < 4; mt++)
#pragma unroll
        for (int nt = 0; nt < 2; nt++) {
            const int e = (wc * 2 + nt) * 16 + fr;
#pragma unroll
            for (int j = 0; j < 4; j++) {
                const int token = m0 + (wr * 4 + mt) * 16 + fg * 4 + j;
                part[((size_t)ks * NTOK + token) * EE + e] = acc[mt][nt][j];
            }
        }
}

// ---------------------------------------------------------------------------
// topk pass 1: wave per token, lane = expert. f32 sum of KS partials + bias
// -> top-2 + third-max. Near-tie rows appended to flagged list (fix kernel
// overwrites them). Output: [gate_probs 16384 f32][indices-as-f32 16384].
// ---------------------------------------------------------------------------
__global__ void moirai_topk(const float* __restrict__ part,
                            const float* __restrict__ bias,
                            float* __restrict__ out,
                            int* __restrict__ count, int* __restrict__ list,
                            int KS) {
    const int lane  = threadIdx.x & 63;
    const int token = blockIdx.x * 4 + (threadIdx.x >> 6);

    float v = bias[lane];
    for (int ks = 0; ks < KS; ks++)
        v += part[((size_t)ks * NTOK + token) * EE + lane];

    // f32 top-2 butterfly with jax tie-break (lower index wins ties)
    float v1 = v, v2 = -3.4e38f;
    int   i1 = lane, i2 = 127;
#pragma unroll
    for (int off = 1; off < 64; off <<= 1) {
        float u1 = __shfl_xor(v1, off);
        float u2 = __shfl_xor(v2, off);
        int   j1 = __shfl_xor(i1, off);
        int   j2 = __shfl_xor(i2, off);
        bool u1_beats_v1 = (u1 > v1) || (u1 == v1 && j1 < i1);
        if (u1_beats_v1) {
            bool v1_beats_u2 = (v1 > u2) || (v1 == u2 && i1 < j2);
            if (v1_beats_u2) { v2 = v1; i2 = i1; }
            else             { v2 = u2; i2 = j2; }
            v1 = u1; i1 = j1;
        } else {
            bool u1_beats_v2 = (u1 > v2) || (u1 == v2 && j1 < i2);
            if (u1_beats_v2) { v2 = u1; i2 = j1; }
        }
    }

    // third-largest value (exclude top-2 by index)
    float ve = (lane == i1 || lane == i2) ? -3.4e38f : v;
#pragma unroll
    for (int off = 1; off < 64; off <<= 1)
        ve = fmaxf(ve, __shfl_xor(ve, off));

    if (lane == 0) {
        if ((v1 - v2 < TAU) || (v2 - ve < TAU)) {
            int pos = atomicAdd(count, 1);
            list[pos] = token;
        }
        double ex = exp((double)v2 - (double)v1);   // v1 >= v2 -> stable
        double s  = 1.0 + ex;
        out[token * 2 + 0] = (float)(1.0 / s);
        out[token * 2 + 1] = (float)(ex / s);
        out[NTOK * 2 + token * 2 + 0] = (float)i1;
        out[NTOK * 2 + token * 2 + 1] = (float)i2;
    }
}

// ---------------------------------------------------------------------------
// fix: exact f64 recompute of flagged rows, one block (1024 thr) per row.
// thread t: expert t&63, k-slice t>>6 (16 x 256). LDS reduce -> wave 0 does
// f64 top-2 (validated tie-break) and overwrites the row's outputs.
// ---------------------------------------------------------------------------
__global__ __launch_bounds__(1024) void moirai_fix(
        const float* __restrict__ x, const float* __restrict__ W,
        const float* __restrict__ bias,
        const int* __restrict__ count, const int* __restrict__ list,
        float* __restrict__ out) {
    __shared__ double red[16][EE];

    const int t = threadIdx.x;
    const int e = t & 63;
    const int q = t >> 6;           // 16 k-slices of 256
    const int n = *count;

    for (int idx = blockIdx.x; idx < n; idx += gridDim.x) {
        const int token = list[idx];
        const float* xr = x + (size_t)token * DD + q * (DD / 16);
        const float* wr = W + (size_t)e * DD + q * (DD / 16);

        double a0 = 0.0, a1 = 0.0, a2 = 0.0, a3 = 0.0;
#pragma unroll 4
        for (int k = 0; k < DD / 16; k += 4) {
            const float4 xv = *(const float4*)(xr + k);
            const float4 wv = *(const float4*)(wr + k);
            a0 += (double)xv.x * (double)wv.x;
            a1 += (double)xv.y * (double)wv.y;
            a2 += (double)xv.z * (double)wv.z;
            a3 += (double)xv.w * (double)wv.w;
        }
        red[q][e] = (a0 + a1) + (a2 + a3);
        __syncthreads();

        if (q == 0) {
            double vd = 0.0;
#pragma unroll
            for (int qq = 0; qq < 16; qq++) vd += red[qq][e];   // fixed order
            vd += (double)bias[e];

            double e1 = vd, e2 = -1.0e300;
            int    f1 = e,  f2 = 127;
#pragma unroll
            for (int off = 1; off < 64; off <<= 1) {
                double u1 = __shfl_xor(e1, off);
                double u2 = __shfl_xor(e2, off);
                int    j1 = __shfl_xor(f1, off);
                int    j2 = __shfl_xor(f2, off);
                bool u1_beats_e1 = (u1 > e1) || (u1 == e1 && j1 < f1);
                if (u1_beats_e1) {
                    bool e1_beats_u2 = (e1 > u2) || (e1 == u2 && f1 < j2);
                    if (e1_beats_u2) { e2 = e1; f2 = f1; }
                    else             { e2 = u2; f2 = j2; }
                    e1 = u1; f1 = j1;
                } else {
                    bool u1_beats_e2 = (u1 > e2) || (u1 == e2 && j1 < f2);
                    if (u1_beats_e2) { e2 = u1; f2 = j1; }
                }
            }

            if (e == 0) {
                double ex = exp(e2 - e1);
                double s  = 1.0 + ex;
                out[token * 2 + 0] = (float)(1.0 / s);
                out[token * 2 + 1] = (float)(ex / s);
                out[NTOK * 2 + token * 2 + 0] = (float)f1;
                out[NTOK * 2 + token * 2 + 1] = (float)f2;
            }
        }
        __syncthreads();   // LDS reuse guard for next grid-stride iteration
    }
}

// ---------------------------------------------------------------------------
extern "C" void kernel_launch(void* const* d_in, const int* in_sizes, int n_in,
                              void* d_out, int out_size, void* d_ws, size_t ws_size,
                              hipStream_t stream) {
    const float* x = (const float*)d_in[0];
    const float* W = (const float*)d_in[1];
    const float* b = (const float*)d_in[2];
    float* out = (float*)d_out;

    // ws layout: [count|list : 64 KB][Wh 512 KB][Wl 512 KB][partials]
    const size_t HDR  = 65536;
    const size_t WSZ  = (size_t)EE * DD * 2;   // 512 KB per split array
    int*            count = (int*)d_ws;
    int*            list  = (int*)d_ws + 1;
    unsigned short* Wh    = (unsigned short*)((char*)d_ws + HDR);
    unsigned short* Wl    = (unsigned short*)((char*)d_ws + HDR + WSZ);
    float*          part  = (float*)((char*)d_ws + HDR + 2 * WSZ);

    int KS = 8;  // K-split; kslen stays a multiple of KC
    while (KS > 1 && HDR + 2 * WSZ + (size_t)KS * NTOK * EE * 4 > ws_size)
        KS >>= 1;
    const int kslen = DD / KS;

    moirai_prep<<<(EE * DD + 255) / 256, 256, 0, stream>>>(W, Wh, Wl, count);
    moirai_gemm<<<NMB * KS, 256, 0, stream>>>(x, Wh, Wl, part, kslen);
    moirai_topk<<<NTOK / 4, 256, 0, stream>>>(part, b, out, count, list, KS);
    moirai_fix<<<256, 1024, 0, stream>>>(x, W, b, count, list, out);
}